// Round 1
// baseline (576.620 us; speedup 1.0000x reference)
//
#include <hip/hip_runtime.h>
#include <hip/hip_bf16.h>

// Problem constants (fixed by reference setup_inputs)
#define NBATCH 128
#define TLEN   2048
#define FDIM   88
#define WIN    64
#define FP     96            // FDIM padded to 96 (multiple of 16/32)
#define TT     128           // time-tile per block
#define FRAMES (TT + WIN)    // 192 staged frames
#define LSTR   104           // LDS frame stride in bf16 elems (pad 96->104 breaks bank pattern)

typedef __attribute__((ext_vector_type(8))) short short8;   // 8 x bf16 (4 VGPR) MFMA A/B frag
typedef __attribute__((ext_vector_type(4))) short short4v;  // 8B LDS store
typedef __attribute__((ext_vector_type(4))) float floatx4;  // MFMA C/D frag

static __device__ __forceinline__ unsigned short f2bf(float f) {
    union { float f; unsigned int u; } a; a.f = f;
    unsigned int u = a.u;
    u += 0x7fffu + ((u >> 16) & 1u);   // round-to-nearest-even
    return (unsigned short)(u >> 16);
}

// Repack W (FDIM x WIN*FDIM, fp32) -> Wt[tau][n=f_out(96)][k=f_in(96)] bf16, zero-padded.
__global__ void prep_w(const float* __restrict__ W, unsigned short* __restrict__ Wt) {
    int idx = blockIdx.x * blockDim.x + threadIdx.x;
    if (idx >= WIN * FP * FP) return;
    int tau = idx / (FP * FP);
    int r   = idx % (FP * FP);
    int n   = r / FP;
    int k   = r % FP;
    float v = 0.f;
    if (n < FDIM && k < FDIM) v = W[n * (WIN * FDIM) + tau * FDIM + k];
    Wt[idx] = f2bf(v);
}

// out[nb, t0+tr, fo] = b[fo] + sum_{tau,fi} x[nb, t0+tr-64+tau, fi] * W[fo, tau*88+fi]
__global__ __launch_bounds__(256) void conv_mfma(
    const float* __restrict__ x, const unsigned short* __restrict__ Wt,
    const float* __restrict__ bias, float* __restrict__ out)
{
    __shared__ unsigned short xs[FRAMES * LSTR];   // 39,936 B

    const int tb  = blockIdx.x;
    const int nb  = blockIdx.y;
    const int t0  = tb * TT;
    const int tid = threadIdx.x;

    // ---- stage x tile: frames [t0-64, t0+TT-1], bf16, zero-padded (time & feature) ----
    const float* xn = x + (size_t)nb * TLEN * FDIM;
    for (int idx = tid; idx < FRAMES * 26; idx += 256) {   // 26 float4-slots per frame (22 real)
        int i = idx / 26;
        int c = idx % 26;
        int g = t0 - WIN + i;
        short4v v = (short4v){0, 0, 0, 0};
        if (c < 22 && g >= 0) {
            float4 f = *((const float4*)(xn + (size_t)g * FDIM) + c);
            v.x = (short)f2bf(f.x); v.y = (short)f2bf(f.y);
            v.z = (short)f2bf(f.z); v.w = (short)f2bf(f.w);
        }
        *(short4v*)&xs[i * LSTR + c * 4] = v;
    }
    __syncthreads();

    // ---- wave tiling: 4 waves, each 64 rows x 48 cols of the 128x96 tile ----
    const int wave = tid >> 6;
    const int lane = tid & 63;
    const int m    = lane & 15;        // MFMA row/col-in-frag index
    const int quad = lane >> 4;        // k-subgroup
    const int wrow = (wave >> 1) * 64; // wave row offset (time)
    const int wcol = (wave & 1) * 48;  // wave col offset (f_out)

    floatx4 acc[4][3] = {};            // [m_t 16-row tiles][n_t 16-col tiles]

    // per-lane base offsets
    const int a_base = (wrow + m) * LSTR + quad * 8;       // + (m_t*16+tau)*LSTR + kk*32
    const unsigned short* wt_lane = Wt + (size_t)(wcol + m) * FP + quad * 8; // + tau*FP*FP + n_t*16*FP + kk*32

    for (int tau = 0; tau < WIN; ++tau) {
        const unsigned short* wt_tau = wt_lane + (size_t)tau * FP * FP;
        const int a_tau = a_base + tau * LSTR;
        #pragma unroll
        for (int kk = 0; kk < 3; ++kk) {
            short8 bf[3];
            #pragma unroll
            for (int n_t = 0; n_t < 3; ++n_t)
                bf[n_t] = *(const short8*)(wt_tau + n_t * 16 * FP + kk * 32);
            short8 af[4];
            #pragma unroll
            for (int m_t = 0; m_t < 4; ++m_t)
                af[m_t] = *(const short8*)&xs[a_tau + m_t * 16 * LSTR + kk * 32];
            #pragma unroll
            for (int m_t = 0; m_t < 4; ++m_t)
                #pragma unroll
                for (int n_t = 0; n_t < 3; ++n_t)
                    acc[m_t][n_t] = __builtin_amdgcn_mfma_f32_16x16x32_bf16(
                        af[m_t], bf[n_t], acc[m_t][n_t], 0, 0, 0);
        }
    }

    // ---- epilogue: D layout col=lane&15, row=quad*4+reg; add bias; write both tuple halves ----
    float bv[3];
    #pragma unroll
    for (int n_t = 0; n_t < 3; ++n_t) {
        int c = wcol + n_t * 16 + m;
        bv[n_t] = (c < FDIM) ? bias[c] : 0.f;
    }
    const size_t half = (size_t)NBATCH * TLEN * FDIM;
    #pragma unroll
    for (int n_t = 0; n_t < 3; ++n_t) {
        int c = wcol + n_t * 16 + m;
        if (c >= FDIM) continue;
        #pragma unroll
        for (int m_t = 0; m_t < 4; ++m_t) {
            #pragma unroll
            for (int reg = 0; reg < 4; ++reg) {
                int tr = wrow + m_t * 16 + quad * 4 + reg;
                size_t off = ((size_t)nb * TLEN + (t0 + tr)) * FDIM + c;
                float v = acc[m_t][n_t][reg] + bv[n_t];
                out[off] = v;
                out[half + off] = v;
            }
        }
    }
}

extern "C" void kernel_launch(void* const* d_in, const int* in_sizes, int n_in,
                              void* d_out, int out_size, void* d_ws, size_t ws_size,
                              hipStream_t stream) {
    const float* x = (const float*)d_in[0];
    const float* W = (const float*)d_in[1];
    const float* b = (const float*)d_in[2];
    float* out = (float*)d_out;
    unsigned short* Wt = (unsigned short*)d_ws;   // 64*96*96*2 = 1,179,648 B

    prep_w<<<(WIN * FP * FP + 255) / 256, 256, 0, stream>>>(W, Wt);
    dim3 grid(TLEN / TT, NBATCH);
    conv_mfma<<<grid, 256, 0, stream>>>(x, Wt, b, out);
}